// Round 18
// baseline (878.548 us; speedup 1.0000x reference)
//
#include <hip/hip_runtime.h>

// GNN forward for MI355X.  (R17 = R16 + k_msg 512-thread/8-wave blocks, shared sW2)
// - counting-sort edges by receiver; Ps=h@Ws, Pr=h@Wr stored SL
//   (slot(c)=(c&15)*8+(c>>4)) so per-edge gather is ONE 16B load per row.
// - k_msg: 8 waves/block share one staged W2 copy (LDS 70.7KB -> 2 blocks/CU
//   = 16 waves/CU, was 12). Per-wave independent run loop (run = 16 sorted
//   edges; run = edge>>4 matches k_fix). Body math identical to R12/R16:
//   t = Ps[s]+Pr[r]+(xe@We+b1 acc-init) -> fast silu -> slot LDS ->
//   msg = t@W2+b2 (swapped MFMA) -> silu -> LDS -> per-wave segmented
//   aggregation (interior -> direct bf16 aggr, boundary -> fp32 pbuf+pid).
// - k_fix (2048 blocks): per node, sum matching pbuf partials -> aggr.
// - k_node: fused node MLP chain, async (T14-split) weight staging.

typedef short bf16x8 __attribute__((ext_vector_type(8)));
typedef float f32x4 __attribute__((ext_vector_type(4)));

union U8 { bf16x8 v; unsigned short u[8]; unsigned int d[4]; };

__device__ __forceinline__ float bf2f(unsigned short u) {
    union { unsigned int i; float f; } x; x.i = ((unsigned int)u) << 16; return x.f;
}
__device__ __forceinline__ float u32lo2f(unsigned int d) {
    union { unsigned int i; float f; } x; x.i = d << 16; return x.f;
}
__device__ __forceinline__ float u32hi2f(unsigned int d) {
    union { unsigned int i; float f; } x; x.i = d & 0xffff0000u; return x.f;
}
__device__ __forceinline__ unsigned short f2bf(float f) {
    union { float f; unsigned int i; } x; x.f = f;
    unsigned int r = x.i + 0x7FFFu + ((x.i >> 16) & 1u);
    return (unsigned short)(r >> 16);
}
__device__ __forceinline__ unsigned int cvt_pk_bf16(float lo, float hi) {
    unsigned int r;
    asm("v_cvt_pk_bf16_f32 %0, %1, %2" : "=v"(r) : "v"(lo), "v"(hi));
    return r;
}
// reference silu (IEEE divide) -- node-side kernels
__device__ __forceinline__ float siluf(float x) { return x / (1.0f + __expf(-x)); }
// fast silu -- k_msg hot path only
__device__ __forceinline__ float silu_fast(float x) {
    float e;
    asm("v_exp_f32 %0, %1" : "=v"(e) : "v"(x * -1.44269504089f));
    float r;
    asm("v_rcp_f32 %0, %1" : "=v"(r) : "v"(e + 1.0f));
    return x * r;
}

// ---------------- setup: counting sort by receiver ----------------
__global__ void k_hist(const int* __restrict__ recv, int* __restrict__ counts, int E) {
    int i = blockIdx.x * 256 + threadIdx.x;
    if (i < E) atomicAdd(&counts[recv[i]], 1);
}

__global__ __launch_bounds__(1024) void k_scan1(const int* __restrict__ counts,
                                                int* __restrict__ offsets,
                                                int* __restrict__ bsum, int n) {
    __shared__ int buf[1024];
    int i = blockIdx.x * 1024 + threadIdx.x;
    int v = (i < n) ? counts[i] : 0;
    buf[threadIdx.x] = v;
    __syncthreads();
    for (int off = 1; off < 1024; off <<= 1) {
        int t = 0;
        if ((int)threadIdx.x >= off) t = buf[threadIdx.x - off];
        __syncthreads();
        if ((int)threadIdx.x >= off) buf[threadIdx.x] += t;
        __syncthreads();
    }
    if (i < n) offsets[i] = buf[threadIdx.x] - v;  // exclusive within block
    if (threadIdx.x == 1023) bsum[blockIdx.x] = buf[1023];
}

__global__ void k_scan2(int* __restrict__ bsum, int nb) {
    if (threadIdx.x == 0 && blockIdx.x == 0) {
        int acc = 0;
        for (int b = 0; b < nb; ++b) { int v = bsum[b]; bsum[b] = acc; acc += v; }
    }
}

__global__ __launch_bounds__(1024) void k_scan3(int* __restrict__ offsets,
                                                const int* __restrict__ bsum,
                                                int n, int E) {
    int i = blockIdx.x * 1024 + threadIdx.x;
    if (i < n) offsets[i] += bsum[blockIdx.x];
    if (i == 0) offsets[n] = E;
}

__global__ void k_scatter(const int* __restrict__ send, const int* __restrict__ recv,
                          const int* __restrict__ offsets, int* __restrict__ cursor,
                          int* __restrict__ ss, int* __restrict__ sr,
                          int* __restrict__ perm, int E) {
    int i = blockIdx.x * 256 + threadIdx.x;
    if (i < E) {
        int r = recv[i];
        int pos = offsets[r] + atomicAdd(&cursor[r], 1);
        ss[pos] = send[i];
        sr[pos] = r;
        perm[pos] = i;
    }
}

__global__ void k_permute_xe(const float* __restrict__ xe, const int* __restrict__ perm,
                             unsigned short* __restrict__ out, int E) {
    int t = blockIdx.x * 256 + threadIdx.x;
    if (t < E * 4) {
        int pos = t >> 2, q = t & 3;
        int e = perm[pos];
        float4 v = *(const float4*)(xe + (size_t)e * 16 + q * 4);
        ushort4 o;
        o.x = f2bf(v.x); o.y = f2bf(v.y); o.z = f2bf(v.z); o.w = f2bf(v.w);
        *(ushort4*)(out + (size_t)pos * 16 + q * 4) = o;
    }
}

// ---------------- weight pre-conversion: fp32 [K][128] -> bf16 [128][K] ----------------
// perm!=0: K-dim stored in SL-slot order (feat(slot) = (slot>>3) + 16*(slot&7))
struct WJob { const float* src; unsigned short* dst; int rows; int perm; };
struct WJobs { WJob j[31]; };

__global__ __launch_bounds__(256) void k_wconv(WJobs jobs) {
    WJob jb = jobs.j[blockIdx.x];
    int n = jb.rows * 128;
    if (jb.perm) {
        for (int i = threadIdx.x; i < n; i += 256) {
            int c = i >> 7, slot = i & 127;
            int feat = (slot >> 3) + 16 * (slot & 7);
            jb.dst[c * 128 + slot] = f2bf(jb.src[feat * 128 + c]);
        }
    } else {
        for (int i = threadIdx.x; i < n; i += 256) {
            int k = i >> 7, c = i & 127;
            jb.dst[c * jb.rows + k] = f2bf(jb.src[i]);
        }
    }
}

// ---------------- embed stage 1 (K=16, VALU) ----------------
__global__ __launch_bounds__(256) void k_embed1(const float* __restrict__ x,
                                                const float* __restrict__ w1,
                                                const float* __restrict__ b1,
                                                unsigned short* __restrict__ out, int N) {
    int idx = blockIdx.x * 256 + threadIdx.x;
    int n = idx >> 6, lane = idx & 63;
    if (n >= N) return;
    const float* xr = x + (size_t)n * 16;
    float xv[16];
#pragma unroll
    for (int k = 0; k < 16; k += 4) {
        float4 v = *(const float4*)(xr + k);
        xv[k] = v.x; xv[k + 1] = v.y; xv[k + 2] = v.z; xv[k + 3] = v.w;
    }
    int c0 = lane * 2;
    float a0 = b1[c0], a1 = b1[c0 + 1];
#pragma unroll
    for (int k = 0; k < 16; ++k) {
        float2 w = *(const float2*)(w1 + k * 128 + c0);
        a0 += xv[k] * w.x; a1 += xv[k] * w.y;
    }
    *(unsigned int*)(out + (size_t)n * 128 + c0) = cvt_pk_bf16(siluf(a0), siluf(a1));
}

// ---------------- shared GEMM helpers ----------------
__device__ __forceinline__ void load_frags(const unsigned short* __restrict__ A,
                                           int r0, int colb, int kg, int M,
                                           bf16x8 (&Af)[2][4]) {
#pragma unroll
    for (int rf = 0; rf < 2; ++rf) {
        int row = r0 + rf * 16 + colb;
        if (row < M) {
#pragma unroll
            for (int ks = 0; ks < 4; ++ks)
                Af[rf][ks] = *(const bf16x8*)(A + (size_t)row * 128 + ks * 32 + kg * 8);
        } else {
            U8 z;
#pragma unroll
            for (int i = 0; i < 8; ++i) z.u[i] = 0;
#pragma unroll
            for (int ks = 0; ks < 4; ++ks) Af[rf][ks] = z.v;
        }
    }
}

__device__ __forceinline__ void mma_block(const bf16x8 (&Af)[2][4],
                                          const unsigned short* sW,
                                          int colb, int kg, f32x4 (&C)[2][8]) {
#pragma unroll
    for (int ks = 0; ks < 4; ++ks) {
#pragma unroll
        for (int cf = 0; cf < 8; ++cf) {
            bf16x8 B = *(const bf16x8*)(sW + (colb + 16 * cf) * 136 + ks * 32 + kg * 8);
#pragma unroll
            for (int rf = 0; rf < 2; ++rf)
                C[rf][cf] = __builtin_amdgcn_mfma_f32_16x16x32_bf16(Af[rf][ks], B, C[rf][cf], 0, 0, 0);
        }
    }
}

// async weight staging: WLOAD issues global loads into regs (early);
// WWRITE commits regs -> LDS inside the standard double-barrier.
#define WLOAD(WT) do { \
    _Pragma("unroll") \
    for (int k_ = 0; k_ < 8; ++k_) \
        wreg[k_] = *(const bf16x8*)((WT) + tid * 8 + k_ * 2048); \
} while (0)

#define WWRITE() do { __syncthreads(); \
    _Pragma("unroll") \
    for (int k_ = 0; k_ < 8; ++k_) { \
        int i_ = tid * 8 + k_ * 2048; \
        *(bf16x8*)(sW + (i_ >> 7) * 136 + (i_ & 127)) = wreg[k_]; \
    } \
    __syncthreads(); } while (0)

// ---------------- fused node kernel (async-staged weights) ----------------
__global__ __launch_bounds__(256, 2) void k_node(
    const unsigned short* __restrict__ A1, const unsigned short* __restrict__ WT1,
    const unsigned short* __restrict__ A2, const unsigned short* __restrict__ WT2,
    const float* __restrict__ b12, int act1,
    unsigned short* __restrict__ out1,
    const unsigned short* __restrict__ WT3, const float* __restrict__ b3,
    unsigned short* __restrict__ out3,
    const unsigned short* __restrict__ WTs, const unsigned short* __restrict__ WTr,
    unsigned short* __restrict__ outPs, unsigned short* __restrict__ outPr,
    int M) {
    __shared__ unsigned short sW[128 * 136];
    __shared__ unsigned short sT[128 * 136];
    int tid = threadIdx.x, lane = tid & 63, w = tid >> 6;
    int r0 = blockIdx.x * 128 + w * 32;
    int colb = lane & 15, kg = lane >> 4;
    bf16x8 wreg[8];

    // ---- stage 1 ----
    f32x4 C[2][8];
#pragma unroll
    for (int cf = 0; cf < 8; ++cf) {
        float bb = b12[colb + 16 * cf];
        C[0][cf] = (f32x4){bb, bb, bb, bb};
        C[1][cf] = C[0][cf];
    }
    bf16x8 Af[2][4], Af2[2][4];
    WLOAD(WT1);
    load_frags(A1, r0, colb, kg, M, Af);           // A loads in flight with W1
    if (WT2) load_frags(A2, r0, colb, kg, M, Af2);
    WWRITE();                                      // W1 -> LDS
    if (WT2) WLOAD(WT2);                           // W2 loads under stage-1 MFMA
    mma_block(Af, sW, colb, kg, C);
    if (WT2) {
        WWRITE();                                  // W2 -> LDS
        if (WT3) WLOAD(WT3);                       // W3 loads under stage-1b MFMA
        mma_block(Af2, sW, colb, kg, C);
    } else if (WT3) {
        WLOAD(WT3);
    }
#pragma unroll
    for (int rf = 0; rf < 2; ++rf) {
#pragma unroll
        for (int cf = 0; cf < 8; ++cf) {
            int col = colb + 16 * cf;
#pragma unroll
            for (int j = 0; j < 4; ++j) {
                float v = C[rf][cf][j];
                if (act1) v = siluf(v);
                unsigned short bv = f2bf(v);
                int lrow = w * 32 + rf * 16 + kg * 4 + j;
                sT[lrow * 136 + col] = bv;
                if (out1) {
                    int row = r0 + rf * 16 + kg * 4 + j;
                    if (row < M) out1[(size_t)row * 128 + col] = bv;
                }
            }
        }
    }

    // ---- stage 2 ----
    if (WT3) {
        WWRITE();  // W3 -> LDS; barriers also order sT writes -> reads
        if (WTs) WLOAD(WTs);  // Ws loads under stage-2 MFMA
        bf16x8 At[2][4];
#pragma unroll
        for (int rf = 0; rf < 2; ++rf)
#pragma unroll
            for (int ks = 0; ks < 4; ++ks)
                At[rf][ks] = *(const bf16x8*)(sT + (w * 32 + rf * 16 + colb) * 136 + ks * 32 + kg * 8);
#pragma unroll
        for (int cf = 0; cf < 8; ++cf) {
            float bb = b3[colb + 16 * cf];
            C[0][cf] = (f32x4){bb, bb, bb, bb};
            C[1][cf] = C[0][cf];
        }
        mma_block(At, sW, colb, kg, C);
#pragma unroll
        for (int rf = 0; rf < 2; ++rf) {
#pragma unroll
            for (int cf = 0; cf < 8; ++cf) {
                int col = colb + 16 * cf;
#pragma unroll
                for (int j = 0; j < 4; ++j) {
                    unsigned short bv = f2bf(C[rf][cf][j]);
                    int row = r0 + rf * 16 + kg * 4 + j;
                    if (row < M) out3[(size_t)row * 128 + col] = bv;
                    if (WTs) sT[(w * 32 + rf * 16 + kg * 4 + j) * 136 + col] = bv;
                }
            }
        }
    } else if (WTs) {
        WLOAD(WTs);
    }

    // ---- stage 3 ----
    if (WTs) {
        WWRITE();  // Ws -> LDS; barriers order sT writes -> reads
        WLOAD(WTr);  // Wr loads under stage-3a MFMA
        bf16x8 At[2][4];
#pragma unroll
        for (int rf = 0; rf < 2; ++rf)
#pragma unroll
            for (int ks = 0; ks < 4; ++ks)
                At[rf][ks] = *(const bf16x8*)(sT + (w * 32 + rf * 16 + colb) * 136 + ks * 32 + kg * 8);
#pragma unroll
        for (int rf = 0; rf < 2; ++rf)
#pragma unroll
            for (int cf = 0; cf < 8; ++cf) C[rf][cf] = (f32x4){0.f, 0.f, 0.f, 0.f};
        mma_block(At, sW, colb, kg, C);
#pragma unroll
        for (int rf = 0; rf < 2; ++rf) {
#pragma unroll
            for (int j = 0; j < 4; ++j) {
                int row = r0 + rf * 16 + kg * 4 + j;
                if (row < M) {
                    U8 o;
#pragma unroll
                    for (int q = 0; q < 4; ++q)
                        o.d[q] = cvt_pk_bf16(C[rf][2 * q][j], C[rf][2 * q + 1][j]);
                    *(bf16x8*)(outPs + (size_t)row * 128 + colb * 8) = o.v;
                }
            }
        }
        WWRITE();  // Wr -> LDS
#pragma unroll
        for (int rf = 0; rf < 2; ++rf)
#pragma unroll
            for (int cf = 0; cf < 8; ++cf) C[rf][cf] = (f32x4){0.f, 0.f, 0.f, 0.f};
        mma_block(At, sW, colb, kg, C);
#pragma unroll
        for (int rf = 0; rf < 2; ++rf) {
#pragma unroll
            for (int j = 0; j < 4; ++j) {
                int row = r0 + rf * 16 + kg * 4 + j;
                if (row < M) {
                    U8 o;
#pragma unroll
                    for (int q = 0; q < 4; ++q)
                        o.d[q] = cvt_pk_bf16(C[rf][2 * q][j], C[rf][2 * q + 1][j]);
                    *(bf16x8*)(outPr + (size_t)row * 128 + colb * 8) = o.v;
                }
            }
        }
    }
}

// ---------------- edge message + fused aggregation (8 waves, shared sW2) ----------------
__global__ __launch_bounds__(512, 2) void k_msg(
    const unsigned short* __restrict__ Ps, const unsigned short* __restrict__ Pr,
    const unsigned short* __restrict__ xes,
    const int* __restrict__ ss, const int* __restrict__ sr,
    const unsigned short* __restrict__ WeT, const float* __restrict__ b1,
    const unsigned short* __restrict__ W2T, const float* __restrict__ b2,
    unsigned short* __restrict__ aggr, float* __restrict__ pbuf,
    int* __restrict__ pid, int nruns) {
    __shared__ unsigned short sW2[128 * 136];  // W2^T [col][slot] (K slot-permuted)
    __shared__ unsigned short sT[128 * 136];   // per-wave 16-row stripes (8 waves)
    __shared__ float sB2[128];
    __shared__ int sRid[128];
    int tid = threadIdx.x, lane = tid & 63, w = tid >> 6;  // w in 0..7
    int colb = lane & 15, kg = lane >> 4;
    int R0 = w * 16, rb4 = kg * 4;

    for (int i = tid * 8; i < 16384; i += 4096)
        *(bf16x8*)(sW2 + (i >> 7) * 136 + (i & 127)) = *(const bf16x8*)(W2T + i);
    if (tid < 128) sB2[tid] = b2[tid];
    bf16x8 WeB[8];
#pragma unroll
    for (int cf = 0; cf < 8; ++cf) {
        if (kg < 2) WeB[cf] = *(const bf16x8*)(WeT + (colb + 16 * cf) * 16 + kg * 8);
        else { U8 z; for (int i = 0; i < 8; ++i) z.u[i] = 0; WeB[cf] = z.v; }
    }
    float b1v[8];
#pragma unroll
    for (int cf = 0; cf < 8; ++cf) b1v[cf] = b1[colb + 16 * cf];
    int s = lane * 2;                      // slot pair for aggregation phase
    int c0 = (s >> 3) + 16 * (s & 7);      // natural feature of slot s (c1 = c0+16)
    __syncthreads();  // sW2/sB2 ready; waves run independently afterwards

    int stride = gridDim.x * 8;            // per-wave run stride
    int run = blockIdx.x * 8 + w;
    if (run >= nruns) return;              // wave-uniform
    U8 zz; for (int i = 0; i < 8; ++i) zz.u[i] = 0;
    bf16x8 Axe = zz.v;
    U8 gp[8];
    int4 s4 = *(const int4*)(ss + (run << 4) + rb4);
    int4 r4 = *(const int4*)(sr + (run << 4) + rb4);

#define ISSUE_GATHER(S4, R4, RR) do { \
        gp[0].v = *(const bf16x8*)(Ps + (size_t)(S4).x * 128 + colb * 8); \
        gp[1].v = *(const bf16x8*)(Ps + (size_t)(S4).y * 128 + colb * 8); \
        gp[2].v = *(const bf16x8*)(Ps + (size_t)(S4).z * 128 + colb * 8); \
        gp[3].v = *(const bf16x8*)(Ps + (size_t)(S4).w * 128 + colb * 8); \
        gp[4].v = *(const bf16x8*)(Pr + (size_t)(R4).x * 128 + colb * 8); \
        gp[5].v = *(const bf16x8*)(Pr + (size_t)(R4).y * 128 + colb * 8); \
        gp[6].v = *(const bf16x8*)(Pr + (size_t)(R4).z * 128 + colb * 8); \
        gp[7].v = *(const bf16x8*)(Pr + (size_t)(R4).w * 128 + colb * 8); \
        if (kg < 2) Axe = *(const bf16x8*)(xes + (size_t)(((RR) << 4) + colb) * 16 + kg * 8); \
    } while (0)

    ISSUE_GATHER(s4, r4, run);
    for (;;) {
        // receiver ids of this wave's 16 edges -> LDS (r4 = CURRENT run)
        if (colb == 0) {
            sRid[R0 + rb4] = r4.x; sRid[R0 + rb4 + 1] = r4.y;
            sRid[R0 + rb4 + 2] = r4.z; sRid[R0 + rb4 + 3] = r4.w;
        }
        int rn = run + stride;
        bool more = rn < nruns;  // wave-uniform
        int4 s4n, r4n;
        if (more) {
            s4n = *(const int4*)(ss + (rn << 4) + rb4);
            r4n = *(const int4*)(sr + (rn << 4) + rb4);
        }
        // MFMA-1: xc = xe@We + b1 (accumulator init)
        f32x4 xc[8];
#pragma unroll
        for (int cf = 0; cf < 8; ++cf) {
            f32x4 bb = (f32x4){b1v[cf], b1v[cf], b1v[cf], b1v[cf]};
            xc[cf] = __builtin_amdgcn_mfma_f32_16x16x32_bf16(Axe, WeB[cf], bb, 0, 0, 0);
        }
        // phase-1: combine + fast silu + cvt_pk -> one b128 write per row (slot order)
#pragma unroll
        for (int j = 0; j < 4; ++j) {
            U8 o;
#pragma unroll
            for (int q = 0; q < 4; ++q) {
                float v0 = u32lo2f(gp[j].d[q]) + u32lo2f(gp[4 + j].d[q]) + xc[2 * q][j];
                float v1 = u32hi2f(gp[j].d[q]) + u32hi2f(gp[4 + j].d[q]) + xc[2 * q + 1][j];
                o.d[q] = cvt_pk_bf16(silu_fast(v0), silu_fast(v1));
            }
            *(bf16x8*)(sT + (R0 + rb4 + j) * 136 + colb * 8) = o.v;
        }
        int rcur = run;
        if (more) ISSUE_GATHER(s4n, r4n, rn);  // prefetch next run under MFMA-2
        asm volatile("s_waitcnt lgkmcnt(0)" ::: "memory");
        __builtin_amdgcn_sched_barrier(0);
        // MFMA-2 swapped: D = W2^T(A) x t^T(B); C col=edge, row=out-feature
        bf16x8 Bt[4];
#pragma unroll
        for (int ks = 0; ks < 4; ++ks)
            Bt[ks] = *(const bf16x8*)(sT + (R0 + colb) * 136 + ks * 32 + kg * 8);
        f32x4 m[8];
#pragma unroll
        for (int acf = 0; acf < 8; ++acf)
            m[acf] = *(const f32x4*)(sB2 + acf * 16 + kg * 4);
#pragma unroll
        for (int ks = 0; ks < 4; ++ks) {
#pragma unroll
            for (int acf = 0; acf < 8; ++acf) {
                bf16x8 Aw = *(const bf16x8*)(sW2 + (16 * acf + colb) * 136 + ks * 32 + kg * 8);
                m[acf] = __builtin_amdgcn_mfma_f32_16x16x32_bf16(Aw, Bt[ks], m[acf], 0, 0, 0);
            }
        }
        // msg (silu'd, bf16) back into the wave's own sT stripe (slot order)
#pragma unroll
        for (int j = 0; j < 4; ++j) {
            U8 o;
#pragma unroll
            for (int q = 0; q < 4; ++q)
                o.d[q] = cvt_pk_bf16(silu_fast(m[2 * q][j]), silu_fast(m[2 * q + 1][j]));
            *(bf16x8*)(sT + (R0 + colb) * 136 + (kg * 4 + j) * 8) = o.v;
        }
        asm volatile("s_waitcnt lgkmcnt(0)" ::: "memory");
        __builtin_amdgcn_sched_barrier(0);
        // segmented aggregation over this wave's 16 sorted edges.
        {
            float a0 = 0.f, a1 = 0.f;
            int prev = sRid[R0];  // uniform across wave
            bool first = true;
            for (int i = 0; i < 16; ++i) {
                int rid = sRid[R0 + i];
                if (rid != prev) {  // wave-uniform branch
                    if (first) {
                        float2 vv; vv.x = a0; vv.y = a1;
                        *(float2*)(pbuf + (size_t)(2 * rcur) * 128 + s) = vv;
                        if (lane == 0) pid[2 * rcur] = prev;
                        first = false;
                    } else {
                        aggr[(size_t)prev * 128 + c0] = f2bf(a0);
                        aggr[(size_t)prev * 128 + c0 + 16] = f2bf(a1);
                    }
                    a0 = 0.f; a1 = 0.f; prev = rid;
                }
                unsigned int v = *(const unsigned int*)(sT + (R0 + i) * 136 + s);
                a0 += u32lo2f(v); a1 += u32hi2f(v);
            }
            float2 vv; vv.x = a0; vv.y = a1;
            if (first) {
                *(float2*)(pbuf + (size_t)(2 * rcur) * 128 + s) = vv;
                if (lane == 0) { pid[2 * rcur] = prev; pid[2 * rcur + 1] = -1; }
            } else {
                *(float2*)(pbuf + (size_t)(2 * rcur + 1) * 128 + s) = vv;
                if (lane == 0) pid[2 * rcur + 1] = prev;
            }
        }
        if (!more) break;
        s4 = s4n; r4 = r4n; run = rn;  // carry NEXT run's indices
    }
#undef ISSUE_GATHER
}

// ---------------- fixup: per node, sum its boundary partials ----------------
__global__ __launch_bounds__(256) void k_fix(
    const float* __restrict__ pbuf, const int* __restrict__ pid,
    const int* __restrict__ offsets, unsigned short* __restrict__ aggr, int N) {
    int gw = (blockIdx.x * 256 + threadIdx.x) >> 6;
    int lane = threadIdx.x & 63;
    int nw = (gridDim.x * 256) >> 6;
    int s = lane * 2;
    int c0 = (s >> 3) + 16 * (s & 7);
    for (int n = gw; n < N; n += nw) {
        int o0 = offsets[n], o1 = offsets[n + 1];
        if (o0 >= o1) continue;  // degree 0: aggr stays 0 (memset once)
        int t0 = o0 >> 4, t1 = (o1 - 1) >> 4;
        // interior of one run: direct-written by k_msg, skip
        if (t0 == t1 && o0 > (t0 << 4) && o1 <= (t0 << 4) + 15) continue;
        float a0 = 0.f, a1 = 0.f;
        for (int tt = t0; tt <= t1; ++tt) {
            if (pid[2 * tt] == n) {
                float2 v = *(const float2*)(pbuf + (size_t)(2 * tt) * 128 + s);
                a0 += v.x; a1 += v.y;
            }
            if (pid[2 * tt + 1] == n) {
                float2 v = *(const float2*)(pbuf + (size_t)(2 * tt + 1) * 128 + s);
                a0 += v.x; a1 += v.y;
            }
        }
        aggr[(size_t)n * 128 + c0] = f2bf(a0);
        aggr[(size_t)n * 128 + c0 + 16] = f2bf(a1);
    }
}

// ---------------- pooling (batch sorted -> contiguous graph ranges) ----------------
__device__ __forceinline__ int lowerb(const int* a, int n, int v) {
    int lo = 0, hi = n;
    while (lo < hi) { int mid = (lo + hi) >> 1; if (a[mid] < v) lo = mid + 1; else hi = mid; }
    return lo;
}

__global__ __launch_bounds__(128) void k_pool(const unsigned short* __restrict__ hpr,
                                              const int* __restrict__ batch,
                                              float* __restrict__ pooled, int N) {
    __shared__ int s_lo, s_hi;
    int g = blockIdx.x;
    if (threadIdx.x == 0) { s_lo = lowerb(batch, N, g); s_hi = lowerb(batch, N, g + 1); }
    __syncthreads();
    int c = threadIdx.x;
    float acc = 0.f;
    for (int r = s_lo; r < s_hi; ++r) acc += bf2f(hpr[(size_t)r * 128 + c]);
    pooled[(size_t)g * 128 + c] = acc;
}

__global__ __launch_bounds__(128) void k_readout(const float* __restrict__ pooled,
                                                 const float* __restrict__ w1,
                                                 const float* __restrict__ b1,
                                                 const float* __restrict__ w2,
                                                 const float* __restrict__ b2,
                                                 float* __restrict__ out) {
    __shared__ float sp[128];
    __shared__ float sred[2];
    int g = blockIdx.x, t = threadIdx.x;
    sp[t] = pooled[(size_t)g * 128 + t];
    __syncthreads();
    float acc = b1[t];
    for (int k = 0; k < 128; ++k) acc += sp[k] * w1[k * 128 + t];
    float val = siluf(acc) * w2[t];
#pragma unroll
    for (int off = 32; off; off >>= 1) val += __shfl_down(val, off);
    if ((t & 63) == 0) sred[t >> 6] = val;
    __syncthreads();
    if (t == 0) out[g] = sred[0] + sred[1] + b2[0];
}

// ---------------- host launcher ----------------
extern "C" void kernel_launch(void* const* d_in, const int* in_sizes, int n_in,
                              void* d_out, int out_size, void* d_ws, size_t ws_size,
                              hipStream_t stream) {
    const float* x_nodes = (const float*)d_in[0];
    const float* x_edges = (const float*)d_in[1];
    const int* edge_index = (const int*)d_in[2];
    const int* batch = (const int*)d_in[3];
    const float* emb_w1 = (const float*)d_in[4];
    const float* emb_b1 = (const float*)d_in[5];
    const float* emb_w2 = (const float*)d_in[6];
    const float* emb_b2 = (const float*)d_in[7];
    const float* ew1 = (const float*)d_in[8];
    const float* eb1 = (const float*)d_in[9];
    const float* ew2 = (const float*)d_in[10];
    const float* eb2 = (const float*)d_in[11];
    const float* nw1 = (const float*)d_in[12];
    const float* nb1 = (const float*)d_in[13];
    const float* nw2 = (const float*)d_in[14];
    const float* nb2 = (const float*)d_in[15];
    const float* pr_w1 = (const float*)d_in[16];
    const float* pr_b1 = (const float*)d_in[17];
    const float* pr_w2 = (const float*)d_in[18];
    const float* pr_b2 = (const float*)d_in[19];
    const float* ro_w1 = (const float*)d_in[20];
    const float* ro_b1 = (const float*)d_in[21];
    const float* ro_w2 = (const float*)d_in[22];
    const float* ro_b2 = (const float*)d_in[23];

    const int N = in_sizes[0] / 16;
    const int E = in_sizes[1] / 16;
    const int G = 512;
    const int L = 4;
    const int nruns = E >> 4;    // 16-edge runs

    char* p = (char*)d_ws;
    auto alloc = [&](size_t bytes) {
        void* r = p;
        p += (bytes + 255) & ~(size_t)255;
        return r;
    };
    int* counts = (int*)alloc((size_t)N * 4);
    int* cursor = (int*)alloc((size_t)N * 4);
    int* offsets = (int*)alloc((size_t)(N + 1) * 4);
    int* bsum = (int*)alloc((size_t)256 * 4);
    int* ss = (int*)alloc((size_t)E * 4);
    int* sr = (int*)alloc((size_t)E * 4);
    int* perm = (int*)alloc((size_t)E * 4);
    unsigned short* xes = (unsigned short*)alloc((size_t)E * 16 * 2);
    unsigned short* h = (unsigned short*)alloc((size_t)N * 128 * 2);
    unsigned short* t0buf = (unsigned short*)alloc((size_t)N * 128 * 2);
    unsigned short* Ps = (unsigned short*)alloc((size_t)N * 128 * 2);
    unsigned short* Pr = (unsigned short*)alloc((size_t)N * 128 * 2);
    unsigned short* aggr = (unsigned short*)alloc((size_t)N * 128 * 2);
    unsigned short* hpr = (unsigned short*)alloc((size_t)N * 128 * 2);
    float* pooled = (float*)alloc((size_t)G * 128 * 4);
    float* pbuf = (float*)alloc((size_t)nruns * 2 * 128 * 4);
    int* pid = (int*)alloc((size_t)nruns * 2 * 4);

    // bf16-transposed weights
    const size_t WSZ = 128 * 128;
    unsigned short* wt_emb2 = (unsigned short*)alloc(WSZ * 2);
    unsigned short *wtWs[4], *wtWr[4], *wtWe[4], *wtW2[4], *wtN1a[4], *wtN1b[4], *wtN2[4];
    for (int l = 0; l < L; ++l) {
        wtWs[l] = (unsigned short*)alloc(WSZ * 2);
        wtWr[l] = (unsigned short*)alloc(WSZ * 2);
        wtWe[l] = (unsigned short*)alloc((size_t)16 * 128 * 2);
        wtW2[l] = (unsigned short*)alloc(WSZ * 2);
        wtN1a[l] = (unsigned short*)alloc(WSZ * 2);
        wtN1b[l] = (unsigned short*)alloc(WSZ * 2);
        wtN2[l] = (unsigned short*)alloc(WSZ * 2);
    }
    unsigned short* wt_pr1 = (unsigned short*)alloc(WSZ * 2);
    unsigned short* wt_pr2 = (unsigned short*)alloc(WSZ * 2);

    const int* send = edge_index;
    const int* recv = edge_index + E;

    // counting sort by receiver (multi-block scan)
    hipMemsetAsync(counts, 0, (size_t)N * 4, stream);
    hipMemsetAsync(cursor, 0, (size_t)N * 4, stream);
    hipMemsetAsync(aggr, 0, (size_t)N * 128 * 2, stream);  // once: covers deg-0 nodes
    k_hist<<<(E + 255) / 256, 256, 0, stream>>>(recv, counts, E);
    int nb = (N + 1023) / 1024;
    k_scan1<<<nb, 1024, 0, stream>>>(counts, offsets, bsum, N);
    k_scan2<<<1, 64, 0, stream>>>(bsum, nb);
    k_scan3<<<nb, 1024, 0, stream>>>(offsets, bsum, N, E);
    k_scatter<<<(E + 255) / 256, 256, 0, stream>>>(send, recv, offsets, cursor, ss, sr, perm, E);
    k_permute_xe<<<(E * 4 + 255) / 256, 256, 0, stream>>>(x_edges, perm, xes, E);

    // weight conversion (perm flags identical to R16)
    WJobs jobs;
    int nj = 0;
    auto addj = [&](const float* s, unsigned short* d, int rows, int pm) {
        jobs.j[nj].src = s; jobs.j[nj].dst = d; jobs.j[nj].rows = rows; jobs.j[nj].perm = pm; ++nj;
    };
    addj(emb_w2, wt_emb2, 128, 0);
    for (int l = 0; l < L; ++l) {
        const float* ew1_l = ew1 + (size_t)l * 272 * 128;
        addj(ew1_l, wtWs[l], 128, 0);
        addj(ew1_l + 128 * 128, wtWr[l], 128, 0);
        addj(ew1_l + 256 * 128, wtWe[l], 16, 0);
        addj(ew2 + (size_t)l * WSZ, wtW2[l], 128, 1);  // slot-permuted K (k_msg)
        const float* nw1_l = nw1 + (size_t)l * 256 * 128;
        addj(nw1_l, wtN1a[l], 128, 0);
        addj(nw1_l + 128 * 128, wtN1b[l], 128, 0);
        addj(nw2 + (size_t)l * WSZ, wtN2[l], 128, 0);
    }
    addj(pr_w1, wt_pr1, 128, 0);
    addj(pr_w2, wt_pr2, 128, 0);
    k_wconv<<<nj, 256, 0, stream>>>(jobs);

    int gb = (N + 127) / 128;
    k_embed1<<<(N * 64 + 255) / 256, 256, 0, stream>>>(x_nodes, emb_w1, emb_b1, t0buf, N);
    k_node<<<gb, 256, 0, stream>>>(t0buf, wt_emb2, nullptr, nullptr, emb_b2, 0,
                                   h, nullptr, nullptr, nullptr,
                                   wtWs[0], wtWr[0], Ps, Pr, N);

    int mg = (nruns + 7) / 8;
    if (mg > 1024) mg = 1024;
    for (int l = 0; l < L; ++l) {
        k_msg<<<mg, 512, 0, stream>>>(Ps, Pr, xes, ss, sr, wtWe[l], eb1 + l * 128,
                                      wtW2[l], eb2 + l * 128, aggr, pbuf, pid, nruns);
        k_fix<<<2048, 256, 0, stream>>>(pbuf, pid, offsets, aggr, N);
        k_node<<<gb, 256, 0, stream>>>(h, wtN1a[l], aggr, wtN1b[l], nb1 + l * 128, 1,
                                       nullptr, wtN2[l], nb2 + l * 128, h,
                                       (l < L - 1) ? wtWs[l + 1] : nullptr,
                                       (l < L - 1) ? wtWr[l + 1] : nullptr,
                                       Ps, Pr, N);
    }

    k_node<<<gb, 256, 0, stream>>>(h, wt_pr1, nullptr, nullptr, pr_b1, 1,
                                   nullptr, wt_pr2, pr_b2, hpr,
                                   nullptr, nullptr, nullptr, nullptr, N);
    k_pool<<<G, 128, 0, stream>>>(hpr, batch, pooled, N);
    k_readout<<<G, 128, 0, stream>>>(pooled, ro_w1, ro_b1, ro_w2, ro_b2, (float*)d_out);
}

// Round 19
// 872.296 us; speedup vs baseline: 1.0072x; 1.0072x over previous
//
#include <hip/hip_runtime.h>

// GNN forward for MI355X.  (R18 = R17 + aggr stored in SL slot layout)
// - counting-sort edges by receiver; Ps=h@Ws, Pr=h@Wr stored SL
//   (slot(c)=(c&15)*8+(c>>4)) so per-edge gather is ONE 16B load per row.
// - k_msg: 8 waves/block share one staged W2 copy (2 blocks/CU = 16 waves/CU).
//   Per-wave independent 16-edge run loop. t = Ps[s]+Pr[r]+(xe@We+b1 acc-init)
//   -> fast silu -> slot LDS -> msg = t@W2+b2 (swapped MFMA) -> silu -> LDS ->
//   per-wave segmented aggregation: interior segments -> ONE packed u32 store
//   per slot-pair into SL-ordered aggr; boundary -> fp32 pbuf+pid. No atomics.
// - k_fix (2048 blocks): per node, sum matching pbuf partials -> aggr (SL).
// - aggr is SL-ordered; its consumer weight wtN1b gets slot-permuted K (free
//   at wconv time) -- same K-permutation invariance as W2.
// - k_node: fused node MLP chain, async (T14-split) weight staging.

typedef short bf16x8 __attribute__((ext_vector_type(8)));
typedef float f32x4 __attribute__((ext_vector_type(4)));

union U8 { bf16x8 v; unsigned short u[8]; unsigned int d[4]; };

__device__ __forceinline__ float bf2f(unsigned short u) {
    union { unsigned int i; float f; } x; x.i = ((unsigned int)u) << 16; return x.f;
}
__device__ __forceinline__ float u32lo2f(unsigned int d) {
    union { unsigned int i; float f; } x; x.i = d << 16; return x.f;
}
__device__ __forceinline__ float u32hi2f(unsigned int d) {
    union { unsigned int i; float f; } x; x.i = d & 0xffff0000u; return x.f;
}
__device__ __forceinline__ unsigned short f2bf(float f) {
    union { float f; unsigned int i; } x; x.f = f;
    unsigned int r = x.i + 0x7FFFu + ((x.i >> 16) & 1u);
    return (unsigned short)(r >> 16);
}
__device__ __forceinline__ unsigned int cvt_pk_bf16(float lo, float hi) {
    unsigned int r;
    asm("v_cvt_pk_bf16_f32 %0, %1, %2" : "=v"(r) : "v"(lo), "v"(hi));
    return r;
}
// reference silu (IEEE divide) -- node-side kernels
__device__ __forceinline__ float siluf(float x) { return x / (1.0f + __expf(-x)); }
// fast silu -- k_msg hot path only
__device__ __forceinline__ float silu_fast(float x) {
    float e;
    asm("v_exp_f32 %0, %1" : "=v"(e) : "v"(x * -1.44269504089f));
    float r;
    asm("v_rcp_f32 %0, %1" : "=v"(r) : "v"(e + 1.0f));
    return x * r;
}

// ---------------- setup: counting sort by receiver ----------------
__global__ void k_hist(const int* __restrict__ recv, int* __restrict__ counts, int E) {
    int i = blockIdx.x * 256 + threadIdx.x;
    if (i < E) atomicAdd(&counts[recv[i]], 1);
}

__global__ __launch_bounds__(1024) void k_scan1(const int* __restrict__ counts,
                                                int* __restrict__ offsets,
                                                int* __restrict__ bsum, int n) {
    __shared__ int buf[1024];
    int i = blockIdx.x * 1024 + threadIdx.x;
    int v = (i < n) ? counts[i] : 0;
    buf[threadIdx.x] = v;
    __syncthreads();
    for (int off = 1; off < 1024; off <<= 1) {
        int t = 0;
        if ((int)threadIdx.x >= off) t = buf[threadIdx.x - off];
        __syncthreads();
        if ((int)threadIdx.x >= off) buf[threadIdx.x] += t;
        __syncthreads();
    }
    if (i < n) offsets[i] = buf[threadIdx.x] - v;  // exclusive within block
    if (threadIdx.x == 1023) bsum[blockIdx.x] = buf[1023];
}

__global__ void k_scan2(int* __restrict__ bsum, int nb) {
    if (threadIdx.x == 0 && blockIdx.x == 0) {
        int acc = 0;
        for (int b = 0; b < nb; ++b) { int v = bsum[b]; bsum[b] = acc; acc += v; }
    }
}

__global__ __launch_bounds__(1024) void k_scan3(int* __restrict__ offsets,
                                                const int* __restrict__ bsum,
                                                int n, int E) {
    int i = blockIdx.x * 1024 + threadIdx.x;
    if (i < n) offsets[i] += bsum[blockIdx.x];
    if (i == 0) offsets[n] = E;
}

__global__ void k_scatter(const int* __restrict__ send, const int* __restrict__ recv,
                          const int* __restrict__ offsets, int* __restrict__ cursor,
                          int* __restrict__ ss, int* __restrict__ sr,
                          int* __restrict__ perm, int E) {
    int i = blockIdx.x * 256 + threadIdx.x;
    if (i < E) {
        int r = recv[i];
        int pos = offsets[r] + atomicAdd(&cursor[r], 1);
        ss[pos] = send[i];
        sr[pos] = r;
        perm[pos] = i;
    }
}

__global__ void k_permute_xe(const float* __restrict__ xe, const int* __restrict__ perm,
                             unsigned short* __restrict__ out, int E) {
    int t = blockIdx.x * 256 + threadIdx.x;
    if (t < E * 4) {
        int pos = t >> 2, q = t & 3;
        int e = perm[pos];
        float4 v = *(const float4*)(xe + (size_t)e * 16 + q * 4);
        ushort4 o;
        o.x = f2bf(v.x); o.y = f2bf(v.y); o.z = f2bf(v.z); o.w = f2bf(v.w);
        *(ushort4*)(out + (size_t)pos * 16 + q * 4) = o;
    }
}

// ---------------- weight pre-conversion: fp32 [K][128] -> bf16 [128][K] ----------------
// perm!=0: K-dim stored in SL-slot order (feat(slot) = (slot>>3) + 16*(slot&7))
struct WJob { const float* src; unsigned short* dst; int rows; int perm; };
struct WJobs { WJob j[31]; };

__global__ __launch_bounds__(256) void k_wconv(WJobs jobs) {
    WJob jb = jobs.j[blockIdx.x];
    int n = jb.rows * 128;
    if (jb.perm) {
        for (int i = threadIdx.x; i < n; i += 256) {
            int c = i >> 7, slot = i & 127;
            int feat = (slot >> 3) + 16 * (slot & 7);
            jb.dst[c * 128 + slot] = f2bf(jb.src[feat * 128 + c]);
        }
    } else {
        for (int i = threadIdx.x; i < n; i += 256) {
            int k = i >> 7, c = i & 127;
            jb.dst[c * jb.rows + k] = f2bf(jb.src[i]);
        }
    }
}

// ---------------- embed stage 1 (K=16, VALU) ----------------
__global__ __launch_bounds__(256) void k_embed1(const float* __restrict__ x,
                                                const float* __restrict__ w1,
                                                const float* __restrict__ b1,
                                                unsigned short* __restrict__ out, int N) {
    int idx = blockIdx.x * 256 + threadIdx.x;
    int n = idx >> 6, lane = idx & 63;
    if (n >= N) return;
    const float* xr = x + (size_t)n * 16;
    float xv[16];
#pragma unroll
    for (int k = 0; k < 16; k += 4) {
        float4 v = *(const float4*)(xr + k);
        xv[k] = v.x; xv[k + 1] = v.y; xv[k + 2] = v.z; xv[k + 3] = v.w;
    }
    int c0 = lane * 2;
    float a0 = b1[c0], a1 = b1[c0 + 1];
#pragma unroll
    for (int k = 0; k < 16; ++k) {
        float2 w = *(const float2*)(w1 + k * 128 + c0);
        a0 += xv[k] * w.x; a1 += xv[k] * w.y;
    }
    *(unsigned int*)(out + (size_t)n * 128 + c0) = cvt_pk_bf16(siluf(a0), siluf(a1));
}

// ---------------- shared GEMM helpers ----------------
__device__ __forceinline__ void load_frags(const unsigned short* __restrict__ A,
                                           int r0, int colb, int kg, int M,
                                           bf16x8 (&Af)[2][4]) {
#pragma unroll
    for (int rf = 0; rf < 2; ++rf) {
        int row = r0 + rf * 16 + colb;
        if (row < M) {
#pragma unroll
            for (int ks = 0; ks < 4; ++ks)
                Af[rf][ks] = *(const bf16x8*)(A + (size_t)row * 128 + ks * 32 + kg * 8);
        } else {
            U8 z;
#pragma unroll
            for (int i = 0; i < 8; ++i) z.u[i] = 0;
#pragma unroll
            for (int ks = 0; ks < 4; ++ks) Af[rf][ks] = z.v;
        }
    }
}

__device__ __forceinline__ void mma_block(const bf16x8 (&Af)[2][4],
                                          const unsigned short* sW,
                                          int colb, int kg, f32x4 (&C)[2][8]) {
#pragma unroll
    for (int ks = 0; ks < 4; ++ks) {
#pragma unroll
        for (int cf = 0; cf < 8; ++cf) {
            bf16x8 B = *(const bf16x8*)(sW + (colb + 16 * cf) * 136 + ks * 32 + kg * 8);
#pragma unroll
            for (int rf = 0; rf < 2; ++rf)
                C[rf][cf] = __builtin_amdgcn_mfma_f32_16x16x32_bf16(Af[rf][ks], B, C[rf][cf], 0, 0, 0);
        }
    }
}

// async weight staging: WLOAD issues global loads into regs (early);
// WWRITE commits regs -> LDS inside the standard double-barrier.
#define WLOAD(WT) do { \
    _Pragma("unroll") \
    for (int k_ = 0; k_ < 8; ++k_) \
        wreg[k_] = *(const bf16x8*)((WT) + tid * 8 + k_ * 2048); \
} while (0)

#define WWRITE() do { __syncthreads(); \
    _Pragma("unroll") \
    for (int k_ = 0; k_ < 8; ++k_) { \
        int i_ = tid * 8 + k_ * 2048; \
        *(bf16x8*)(sW + (i_ >> 7) * 136 + (i_ & 127)) = wreg[k_]; \
    } \
    __syncthreads(); } while (0)

// ---------------- fused node kernel (async-staged weights) ----------------
__global__ __launch_bounds__(256, 2) void k_node(
    const unsigned short* __restrict__ A1, const unsigned short* __restrict__ WT1,
    const unsigned short* __restrict__ A2, const unsigned short* __restrict__ WT2,
    const float* __restrict__ b12, int act1,
    unsigned short* __restrict__ out1,
    const unsigned short* __restrict__ WT3, const float* __restrict__ b3,
    unsigned short* __restrict__ out3,
    const unsigned short* __restrict__ WTs, const unsigned short* __restrict__ WTr,
    unsigned short* __restrict__ outPs, unsigned short* __restrict__ outPr,
    int M) {
    __shared__ unsigned short sW[128 * 136];
    __shared__ unsigned short sT[128 * 136];
    int tid = threadIdx.x, lane = tid & 63, w = tid >> 6;
    int r0 = blockIdx.x * 128 + w * 32;
    int colb = lane & 15, kg = lane >> 4;
    bf16x8 wreg[8];

    // ---- stage 1 ----
    f32x4 C[2][8];
#pragma unroll
    for (int cf = 0; cf < 8; ++cf) {
        float bb = b12[colb + 16 * cf];
        C[0][cf] = (f32x4){bb, bb, bb, bb};
        C[1][cf] = C[0][cf];
    }
    bf16x8 Af[2][4], Af2[2][4];
    WLOAD(WT1);
    load_frags(A1, r0, colb, kg, M, Af);           // A loads in flight with W1
    if (WT2) load_frags(A2, r0, colb, kg, M, Af2);
    WWRITE();                                      // W1 -> LDS
    if (WT2) WLOAD(WT2);                           // W2 loads under stage-1 MFMA
    mma_block(Af, sW, colb, kg, C);
    if (WT2) {
        WWRITE();                                  // W2 -> LDS
        if (WT3) WLOAD(WT3);                       // W3 loads under stage-1b MFMA
        mma_block(Af2, sW, colb, kg, C);
    } else if (WT3) {
        WLOAD(WT3);
    }
#pragma unroll
    for (int rf = 0; rf < 2; ++rf) {
#pragma unroll
        for (int cf = 0; cf < 8; ++cf) {
            int col = colb + 16 * cf;
#pragma unroll
            for (int j = 0; j < 4; ++j) {
                float v = C[rf][cf][j];
                if (act1) v = siluf(v);
                unsigned short bv = f2bf(v);
                int lrow = w * 32 + rf * 16 + kg * 4 + j;
                sT[lrow * 136 + col] = bv;
                if (out1) {
                    int row = r0 + rf * 16 + kg * 4 + j;
                    if (row < M) out1[(size_t)row * 128 + col] = bv;
                }
            }
        }
    }

    // ---- stage 2 ----
    if (WT3) {
        WWRITE();  // W3 -> LDS; barriers also order sT writes -> reads
        if (WTs) WLOAD(WTs);  // Ws loads under stage-2 MFMA
        bf16x8 At[2][4];
#pragma unroll
        for (int rf = 0; rf < 2; ++rf)
#pragma unroll
            for (int ks = 0; ks < 4; ++ks)
                At[rf][ks] = *(const bf16x8*)(sT + (w * 32 + rf * 16 + colb) * 136 + ks * 32 + kg * 8);
#pragma unroll
        for (int cf = 0; cf < 8; ++cf) {
            float bb = b3[colb + 16 * cf];
            C[0][cf] = (f32x4){bb, bb, bb, bb};
            C[1][cf] = C[0][cf];
        }
        mma_block(At, sW, colb, kg, C);
#pragma unroll
        for (int rf = 0; rf < 2; ++rf) {
#pragma unroll
            for (int cf = 0; cf < 8; ++cf) {
                int col = colb + 16 * cf;
#pragma unroll
                for (int j = 0; j < 4; ++j) {
                    unsigned short bv = f2bf(C[rf][cf][j]);
                    int row = r0 + rf * 16 + kg * 4 + j;
                    if (row < M) out3[(size_t)row * 128 + col] = bv;
                    if (WTs) sT[(w * 32 + rf * 16 + kg * 4 + j) * 136 + col] = bv;
                }
            }
        }
    } else if (WTs) {
        WLOAD(WTs);
    }

    // ---- stage 3 ----
    if (WTs) {
        WWRITE();  // Ws -> LDS; barriers order sT writes -> reads
        WLOAD(WTr);  // Wr loads under stage-3a MFMA
        bf16x8 At[2][4];
#pragma unroll
        for (int rf = 0; rf < 2; ++rf)
#pragma unroll
            for (int ks = 0; ks < 4; ++ks)
                At[rf][ks] = *(const bf16x8*)(sT + (w * 32 + rf * 16 + colb) * 136 + ks * 32 + kg * 8);
#pragma unroll
        for (int rf = 0; rf < 2; ++rf)
#pragma unroll
            for (int cf = 0; cf < 8; ++cf) C[rf][cf] = (f32x4){0.f, 0.f, 0.f, 0.f};
        mma_block(At, sW, colb, kg, C);
#pragma unroll
        for (int rf = 0; rf < 2; ++rf) {
#pragma unroll
            for (int j = 0; j < 4; ++j) {
                int row = r0 + rf * 16 + kg * 4 + j;
                if (row < M) {
                    U8 o;
#pragma unroll
                    for (int q = 0; q < 4; ++q)
                        o.d[q] = cvt_pk_bf16(C[rf][2 * q][j], C[rf][2 * q + 1][j]);
                    *(bf16x8*)(outPs + (size_t)row * 128 + colb * 8) = o.v;
                }
            }
        }
        WWRITE();  // Wr -> LDS
#pragma unroll
        for (int rf = 0; rf < 2; ++rf)
#pragma unroll
            for (int cf = 0; cf < 8; ++cf) C[rf][cf] = (f32x4){0.f, 0.f, 0.f, 0.f};
        mma_block(At, sW, colb, kg, C);
#pragma unroll
        for (int rf = 0; rf < 2; ++rf) {
#pragma unroll
            for (int j = 0; j < 4; ++j) {
                int row = r0 + rf * 16 + kg * 4 + j;
                if (row < M) {
                    U8 o;
#pragma unroll
                    for (int q = 0; q < 4; ++q)
                        o.d[q] = cvt_pk_bf16(C[rf][2 * q][j], C[rf][2 * q + 1][j]);
                    *(bf16x8*)(outPr + (size_t)row * 128 + colb * 8) = o.v;
                }
            }
        }
    }
}

// ---------------- edge message + fused aggregation (8 waves, shared sW2) ----------------
__global__ __launch_bounds__(512, 2) void k_msg(
    const unsigned short* __restrict__ Ps, const unsigned short* __restrict__ Pr,
    const unsigned short* __restrict__ xes,
    const int* __restrict__ ss, const int* __restrict__ sr,
    const unsigned short* __restrict__ WeT, const float* __restrict__ b1,
    const unsigned short* __restrict__ W2T, const float* __restrict__ b2,
    unsigned short* __restrict__ aggr, float* __restrict__ pbuf,
    int* __restrict__ pid, int nruns) {
    __shared__ unsigned short sW2[128 * 136];  // W2^T [col][slot] (K slot-permuted)
    __shared__ unsigned short sT[128 * 136];   // per-wave 16-row stripes (8 waves)
    __shared__ float sB2[128];
    __shared__ int sRid[128];
    int tid = threadIdx.x, lane = tid & 63, w = tid >> 6;  // w in 0..7
    int colb = lane & 15, kg = lane >> 4;
    int R0 = w * 16, rb4 = kg * 4;

    for (int i = tid * 8; i < 16384; i += 4096)
        *(bf16x8*)(sW2 + (i >> 7) * 136 + (i & 127)) = *(const bf16x8*)(W2T + i);
    if (tid < 128) sB2[tid] = b2[tid];
    bf16x8 WeB[8];
#pragma unroll
    for (int cf = 0; cf < 8; ++cf) {
        if (kg < 2) WeB[cf] = *(const bf16x8*)(WeT + (colb + 16 * cf) * 16 + kg * 8);
        else { U8 z; for (int i = 0; i < 8; ++i) z.u[i] = 0; WeB[cf] = z.v; }
    }
    float b1v[8];
#pragma unroll
    for (int cf = 0; cf < 8; ++cf) b1v[cf] = b1[colb + 16 * cf];
    int s = lane * 2;                      // slot pair for aggregation phase (SL aggr)
    __syncthreads();  // sW2/sB2 ready; waves run independently afterwards

    int stride = gridDim.x * 8;            // per-wave run stride
    int run = blockIdx.x * 8 + w;
    if (run >= nruns) return;              // wave-uniform
    U8 zz; for (int i = 0; i < 8; ++i) zz.u[i] = 0;
    bf16x8 Axe = zz.v;
    U8 gp[8];
    int4 s4 = *(const int4*)(ss + (run << 4) + rb4);
    int4 r4 = *(const int4*)(sr + (run << 4) + rb4);

#define ISSUE_GATHER(S4, R4, RR) do { \
        gp[0].v = *(const bf16x8*)(Ps + (size_t)(S4).x * 128 + colb * 8); \
        gp[1].v = *(const bf16x8*)(Ps + (size_t)(S4).y * 128 + colb * 8); \
        gp[2].v = *(const bf16x8*)(Ps + (size_t)(S4).z * 128 + colb * 8); \
        gp[3].v = *(const bf16x8*)(Ps + (size_t)(S4).w * 128 + colb * 8); \
        gp[4].v = *(const bf16x8*)(Pr + (size_t)(R4).x * 128 + colb * 8); \
        gp[5].v = *(const bf16x8*)(Pr + (size_t)(R4).y * 128 + colb * 8); \
        gp[6].v = *(const bf16x8*)(Pr + (size_t)(R4).z * 128 + colb * 8); \
        gp[7].v = *(const bf16x8*)(Pr + (size_t)(R4).w * 128 + colb * 8); \
        if (kg < 2) Axe = *(const bf16x8*)(xes + (size_t)(((RR) << 4) + colb) * 16 + kg * 8); \
    } while (0)

    ISSUE_GATHER(s4, r4, run);
    for (;;) {
        // receiver ids of this wave's 16 edges -> LDS (r4 = CURRENT run)
        if (colb == 0) {
            sRid[R0 + rb4] = r4.x; sRid[R0 + rb4 + 1] = r4.y;
            sRid[R0 + rb4 + 2] = r4.z; sRid[R0 + rb4 + 3] = r4.w;
        }
        int rn = run + stride;
        bool more = rn < nruns;  // wave-uniform
        int4 s4n, r4n;
        if (more) {
            s4n = *(const int4*)(ss + (rn << 4) + rb4);
            r4n = *(const int4*)(sr + (rn << 4) + rb4);
        }
        // MFMA-1: xc = xe@We + b1 (accumulator init)
        f32x4 xc[8];
#pragma unroll
        for (int cf = 0; cf < 8; ++cf) {
            f32x4 bb = (f32x4){b1v[cf], b1v[cf], b1v[cf], b1v[cf]};
            xc[cf] = __builtin_amdgcn_mfma_f32_16x16x32_bf16(Axe, WeB[cf], bb, 0, 0, 0);
        }
        // phase-1: combine + fast silu + cvt_pk -> one b128 write per row (slot order)
#pragma unroll
        for (int j = 0; j < 4; ++j) {
            U8 o;
#pragma unroll
            for (int q = 0; q < 4; ++q) {
                float v0 = u32lo2f(gp[j].d[q]) + u32lo2f(gp[4 + j].d[q]) + xc[2 * q][j];
                float v1 = u32hi2f(gp[j].d[q]) + u32hi2f(gp[4 + j].d[q]) + xc[2 * q + 1][j];
                o.d[q] = cvt_pk_bf16(silu_fast(v0), silu_fast(v1));
            }
            *(bf16x8*)(sT + (R0 + rb4 + j) * 136 + colb * 8) = o.v;
        }
        int rcur = run;
        if (more) ISSUE_GATHER(s4n, r4n, rn);  // prefetch next run under MFMA-2
        asm volatile("s_waitcnt lgkmcnt(0)" ::: "memory");
        __builtin_amdgcn_sched_barrier(0);
        // MFMA-2 swapped: D = W2^T(A) x t^T(B); C col=edge, row=out-feature
        bf16x8 Bt[4];
#pragma unroll
        for (int ks = 0; ks < 4; ++ks)
            Bt[ks] = *(const bf16x8*)(sT + (R0 + colb) * 136 + ks * 32 + kg * 8);
        f32x4 m[8];
#pragma unroll
        for (int acf = 0; acf < 8; ++acf)
            m[acf] = *(const f32x4*)(sB2 + acf * 16 + kg * 4);
#pragma unroll
        for (int ks = 0; ks < 4; ++ks) {
#pragma unroll
            for (int acf = 0; acf < 8; ++acf) {
                bf16x8 Aw = *(const bf16x8*)(sW2 + (16 * acf + colb) * 136 + ks * 32 + kg * 8);
                m[acf] = __builtin_amdgcn_mfma_f32_16x16x32_bf16(Aw, Bt[ks], m[acf], 0, 0, 0);
            }
        }
        // msg (silu'd, bf16) back into the wave's own sT stripe (slot order)
#pragma unroll
        for (int j = 0; j < 4; ++j) {
            U8 o;
#pragma unroll
            for (int q = 0; q < 4; ++q)
                o.d[q] = cvt_pk_bf16(silu_fast(m[2 * q][j]), silu_fast(m[2 * q + 1][j]));
            *(bf16x8*)(sT + (R0 + colb) * 136 + (kg * 4 + j) * 8) = o.v;
        }
        asm volatile("s_waitcnt lgkmcnt(0)" ::: "memory");
        __builtin_amdgcn_sched_barrier(0);
        // segmented aggregation over this wave's 16 sorted edges.
        // aggr is SL-ordered: slot pair s,s+1 adjacent -> one packed u32 store.
        {
            float a0 = 0.f, a1 = 0.f;
            int prev = sRid[R0];  // uniform across wave
            bool first = true;
            for (int i = 0; i < 16; ++i) {
                int rid = sRid[R0 + i];
                if (rid != prev) {  // wave-uniform branch
                    if (first) {
                        float2 vv; vv.x = a0; vv.y = a1;
                        *(float2*)(pbuf + (size_t)(2 * rcur) * 128 + s) = vv;
                        if (lane == 0) pid[2 * rcur] = prev;
                        first = false;
                    } else {
                        *(unsigned int*)(aggr + (size_t)prev * 128 + s) = cvt_pk_bf16(a0, a1);
                    }
                    a0 = 0.f; a1 = 0.f; prev = rid;
                }
                unsigned int v = *(const unsigned int*)(sT + (R0 + i) * 136 + s);
                a0 += u32lo2f(v); a1 += u32hi2f(v);
            }
            float2 vv; vv.x = a0; vv.y = a1;
            if (first) {
                *(float2*)(pbuf + (size_t)(2 * rcur) * 128 + s) = vv;
                if (lane == 0) { pid[2 * rcur] = prev; pid[2 * rcur + 1] = -1; }
            } else {
                *(float2*)(pbuf + (size_t)(2 * rcur + 1) * 128 + s) = vv;
                if (lane == 0) pid[2 * rcur + 1] = prev;
            }
        }
        if (!more) break;
        s4 = s4n; r4 = r4n; run = rn;  // carry NEXT run's indices
    }
#undef ISSUE_GATHER
}

// ---------------- fixup: per node, sum its boundary partials (SL aggr) ----------------
__global__ __launch_bounds__(256) void k_fix(
    const float* __restrict__ pbuf, const int* __restrict__ pid,
    const int* __restrict__ offsets, unsigned short* __restrict__ aggr, int N) {
    int gw = (blockIdx.x * 256 + threadIdx.x) >> 6;
    int lane = threadIdx.x & 63;
    int nw = (gridDim.x * 256) >> 6;
    int s = lane * 2;
    for (int n = gw; n < N; n += nw) {
        int o0 = offsets[n], o1 = offsets[n + 1];
        if (o0 >= o1) continue;  // degree 0: aggr stays 0 (memset once)
        int t0 = o0 >> 4, t1 = (o1 - 1) >> 4;
        // interior of one run: direct-written by k_msg, skip
        if (t0 == t1 && o0 > (t0 << 4) && o1 <= (t0 << 4) + 15) continue;
        float a0 = 0.f, a1 = 0.f;
        for (int tt = t0; tt <= t1; ++tt) {
            if (pid[2 * tt] == n) {
                float2 v = *(const float2*)(pbuf + (size_t)(2 * tt) * 128 + s);
                a0 += v.x; a1 += v.y;
            }
            if (pid[2 * tt + 1] == n) {
                float2 v = *(const float2*)(pbuf + (size_t)(2 * tt + 1) * 128 + s);
                a0 += v.x; a1 += v.y;
            }
        }
        *(unsigned int*)(aggr + (size_t)n * 128 + s) = cvt_pk_bf16(a0, a1);
    }
}

// ---------------- pooling (batch sorted -> contiguous graph ranges) ----------------
__device__ __forceinline__ int lowerb(const int* a, int n, int v) {
    int lo = 0, hi = n;
    while (lo < hi) { int mid = (lo + hi) >> 1; if (a[mid] < v) lo = mid + 1; else hi = mid; }
    return lo;
}

__global__ __launch_bounds__(128) void k_pool(const unsigned short* __restrict__ hpr,
                                              const int* __restrict__ batch,
                                              float* __restrict__ pooled, int N) {
    __shared__ int s_lo, s_hi;
    int g = blockIdx.x;
    if (threadIdx.x == 0) { s_lo = lowerb(batch, N, g); s_hi = lowerb(batch, N, g + 1); }
    __syncthreads();
    int c = threadIdx.x;
    float acc = 0.f;
    for (int r = s_lo; r < s_hi; ++r) acc += bf2f(hpr[(size_t)r * 128 + c]);
    pooled[(size_t)g * 128 + c] = acc;
}

__global__ __launch_bounds__(128) void k_readout(const float* __restrict__ pooled,
                                                 const float* __restrict__ w1,
                                                 const float* __restrict__ b1,
                                                 const float* __restrict__ w2,
                                                 const float* __restrict__ b2,
                                                 float* __restrict__ out) {
    __shared__ float sp[128];
    __shared__ float sred[2];
    int g = blockIdx.x, t = threadIdx.x;
    sp[t] = pooled[(size_t)g * 128 + t];
    __syncthreads();
    float acc = b1[t];
    for (int k = 0; k < 128; ++k) acc += sp[k] * w1[k * 128 + t];
    float val = siluf(acc) * w2[t];
#pragma unroll
    for (int off = 32; off; off >>= 1) val += __shfl_down(val, off);
    if ((t & 63) == 0) sred[t >> 6] = val;
    __syncthreads();
    if (t == 0) out[g] = sred[0] + sred[1] + b2[0];
}

// ---------------- host launcher ----------------
extern "C" void kernel_launch(void* const* d_in, const int* in_sizes, int n_in,
                              void* d_out, int out_size, void* d_ws, size_t ws_size,
                              hipStream_t stream) {
    const float* x_nodes = (const float*)d_in[0];
    const float* x_edges = (const float*)d_in[1];
    const int* edge_index = (const int*)d_in[2];
    const int* batch = (const int*)d_in[3];
    const float* emb_w1 = (const float*)d_in[4];
    const float* emb_b1 = (const float*)d_in[5];
    const float* emb_w2 = (const float*)d_in[6];
    const float* emb_b2 = (const float*)d_in[7];
    const float* ew1 = (const float*)d_in[8];
    const float* eb1 = (const float*)d_in[9];
    const float* ew2 = (const float*)d_in[10];
    const float* eb2 = (const float*)d_in[11];
    const float* nw1 = (const float*)d_in[12];
    const float* nb1 = (const float*)d_in[13];
    const float* nw2 = (const float*)d_in[14];
    const float* nb2 = (const float*)d_in[15];
    const float* pr_w1 = (const float*)d_in[16];
    const float* pr_b1 = (const float*)d_in[17];
    const float* pr_w2 = (const float*)d_in[18];
    const float* pr_b2 = (const float*)d_in[19];
    const float* ro_w1 = (const float*)d_in[20];
    const float* ro_b1 = (const float*)d_in[21];
    const float* ro_w2 = (const float*)d_in[22];
    const float* ro_b2 = (const float*)d_in[23];

    const int N = in_sizes[0] / 16;
    const int E = in_sizes[1] / 16;
    const int G = 512;
    const int L = 4;
    const int nruns = E >> 4;    // 16-edge runs

    char* p = (char*)d_ws;
    auto alloc = [&](size_t bytes) {
        void* r = p;
        p += (bytes + 255) & ~(size_t)255;
        return r;
    };
    int* counts = (int*)alloc((size_t)N * 4);
    int* cursor = (int*)alloc((size_t)N * 4);
    int* offsets = (int*)alloc((size_t)(N + 1) * 4);
    int* bsum = (int*)alloc((size_t)256 * 4);
    int* ss = (int*)alloc((size_t)E * 4);
    int* sr = (int*)alloc((size_t)E * 4);
    int* perm = (int*)alloc((size_t)E * 4);
    unsigned short* xes = (unsigned short*)alloc((size_t)E * 16 * 2);
    unsigned short* h = (unsigned short*)alloc((size_t)N * 128 * 2);
    unsigned short* t0buf = (unsigned short*)alloc((size_t)N * 128 * 2);
    unsigned short* Ps = (unsigned short*)alloc((size_t)N * 128 * 2);
    unsigned short* Pr = (unsigned short*)alloc((size_t)N * 128 * 2);
    unsigned short* aggr = (unsigned short*)alloc((size_t)N * 128 * 2);
    unsigned short* hpr = (unsigned short*)alloc((size_t)N * 128 * 2);
    float* pooled = (float*)alloc((size_t)G * 128 * 4);
    float* pbuf = (float*)alloc((size_t)nruns * 2 * 128 * 4);
    int* pid = (int*)alloc((size_t)nruns * 2 * 4);

    // bf16-transposed weights
    const size_t WSZ = 128 * 128;
    unsigned short* wt_emb2 = (unsigned short*)alloc(WSZ * 2);
    unsigned short *wtWs[4], *wtWr[4], *wtWe[4], *wtW2[4], *wtN1a[4], *wtN1b[4], *wtN2[4];
    for (int l = 0; l < L; ++l) {
        wtWs[l] = (unsigned short*)alloc(WSZ * 2);
        wtWr[l] = (unsigned short*)alloc(WSZ * 2);
        wtWe[l] = (unsigned short*)alloc((size_t)16 * 128 * 2);
        wtW2[l] = (unsigned short*)alloc(WSZ * 2);
        wtN1a[l] = (unsigned short*)alloc(WSZ * 2);
        wtN1b[l] = (unsigned short*)alloc(WSZ * 2);
        wtN2[l] = (unsigned short*)alloc(WSZ * 2);
    }
    unsigned short* wt_pr1 = (unsigned short*)alloc(WSZ * 2);
    unsigned short* wt_pr2 = (unsigned short*)alloc(WSZ * 2);

    const int* send = edge_index;
    const int* recv = edge_index + E;

    // counting sort by receiver (multi-block scan)
    hipMemsetAsync(counts, 0, (size_t)N * 4, stream);
    hipMemsetAsync(cursor, 0, (size_t)N * 4, stream);
    hipMemsetAsync(aggr, 0, (size_t)N * 128 * 2, stream);  // once: covers deg-0 nodes
    k_hist<<<(E + 255) / 256, 256, 0, stream>>>(recv, counts, E);
    int nb = (N + 1023) / 1024;
    k_scan1<<<nb, 1024, 0, stream>>>(counts, offsets, bsum, N);
    k_scan2<<<1, 64, 0, stream>>>(bsum, nb);
    k_scan3<<<nb, 1024, 0, stream>>>(offsets, bsum, N, E);
    k_scatter<<<(E + 255) / 256, 256, 0, stream>>>(send, recv, offsets, cursor, ss, sr, perm, E);
    k_permute_xe<<<(E * 4 + 255) / 256, 256, 0, stream>>>(x_edges, perm, xes, E);

    // weight conversion (wtN1b now slot-permuted K: consumes SL aggr)
    WJobs jobs;
    int nj = 0;
    auto addj = [&](const float* s, unsigned short* d, int rows, int pm) {
        jobs.j[nj].src = s; jobs.j[nj].dst = d; jobs.j[nj].rows = rows; jobs.j[nj].perm = pm; ++nj;
    };
    addj(emb_w2, wt_emb2, 128, 0);
    for (int l = 0; l < L; ++l) {
        const float* ew1_l = ew1 + (size_t)l * 272 * 128;
        addj(ew1_l, wtWs[l], 128, 0);
        addj(ew1_l + 128 * 128, wtWr[l], 128, 0);
        addj(ew1_l + 256 * 128, wtWe[l], 16, 0);
        addj(ew2 + (size_t)l * WSZ, wtW2[l], 128, 1);  // slot-permuted K (k_msg t)
        const float* nw1_l = nw1 + (size_t)l * 256 * 128;
        addj(nw1_l, wtN1a[l], 128, 0);
        addj(nw1_l + 128 * 128, wtN1b[l], 128, 1);     // slot-permuted K (SL aggr)
        addj(nw2 + (size_t)l * WSZ, wtN2[l], 128, 0);
    }
    addj(pr_w1, wt_pr1, 128, 0);
    addj(pr_w2, wt_pr2, 128, 0);
    k_wconv<<<nj, 256, 0, stream>>>(jobs);

    int gb = (N + 127) / 128;
    k_embed1<<<(N * 64 + 255) / 256, 256, 0, stream>>>(x_nodes, emb_w1, emb_b1, t0buf, N);
    k_node<<<gb, 256, 0, stream>>>(t0buf, wt_emb2, nullptr, nullptr, emb_b2, 0,
                                   h, nullptr, nullptr, nullptr,
                                   wtWs[0], wtWr[0], Ps, Pr, N);

    int mg = (nruns + 7) / 8;
    if (mg > 1024) mg = 1024;
    for (int l = 0; l < L; ++l) {
        k_msg<<<mg, 512, 0, stream>>>(Ps, Pr, xes, ss, sr, wtWe[l], eb1 + l * 128,
                                      wtW2[l], eb2 + l * 128, aggr, pbuf, pid, nruns);
        k_fix<<<2048, 256, 0, stream>>>(pbuf, pid, offsets, aggr, N);
        k_node<<<gb, 256, 0, stream>>>(h, wtN1a[l], aggr, wtN1b[l], nb1 + l * 128, 1,
                                       nullptr, wtN2[l], nb2 + l * 128, h,
                                       (l < L - 1) ? wtWs[l + 1] : nullptr,
                                       (l < L - 1) ? wtWr[l + 1] : nullptr,
                                       Ps, Pr, N);
    }

    k_node<<<gb, 256, 0, stream>>>(h, wt_pr1, nullptr, nullptr, pr_b1, 1,
                                   nullptr, wt_pr2, pr_b2, hpr,
                                   nullptr, nullptr, nullptr, nullptr, N);
    k_pool<<<G, 128, 0, stream>>>(hpr, batch, pooled, N);
    k_readout<<<G, 128, 0, stream>>>(pooled, ro_w1, ro_b1, ro_w2, ro_b2, (float*)d_out);
}